// Round 1
// baseline (474.015 us; speedup 1.0000x reference)
//
#include <hip/hip_runtime.h>
#include <hip/hip_bf16.h>

#define TQ 2048
#define HIDDEN 1024
#define NB 4
#define NH 16
#define DH 64
#define BHN (NB*NH)   // 64

typedef __attribute__((ext_vector_type(4))) float f32x4;
typedef __attribute__((ext_vector_type(8))) short s16x8;

__device__ inline unsigned short f2bf(float f) {
    union { float f; unsigned int u; } x; x.f = f;
    unsigned int r = x.u + 0x7fffu + ((x.u >> 16) & 1u);
    return (unsigned short)(r >> 16);
}

// ---------------------------------------------------------------------------
// Weight transpose+convert: Wt[n][k] = bf16(W[k][n]); 4 weights via blockIdx.z
// ---------------------------------------------------------------------------
__global__ __launch_bounds__(256) void wt_kernel(const float* W0, const float* W1,
                                                 const float* W2, const float* W3,
                                                 unsigned short* Wt) {
    const float* W = (blockIdx.z == 0) ? W0 : (blockIdx.z == 1) ? W1
                    : (blockIdx.z == 2) ? W2 : W3;
    unsigned short* out = Wt + (size_t)blockIdx.z * HIDDEN * HIDDEN;
    __shared__ float tile[64][68];
    int t = threadIdx.x;
    int k0 = blockIdx.y * 64, n0 = blockIdx.x * 64;
#pragma unroll
    for (int i = 0; i < 4; i++) {
        int r = (t >> 4) + i * 16;
        int c = (t & 15) * 4;
        float4 v = *(const float4*)(W + (size_t)(k0 + r) * HIDDEN + n0 + c);
        tile[r][c] = v.x; tile[r][c+1] = v.y; tile[r][c+2] = v.z; tile[r][c+3] = v.w;
    }
    __syncthreads();
#pragma unroll
    for (int i = 0; i < 4; i++) {
        int n = (t >> 4) + i * 16;
        int kc = (t & 15) * 4;
        ushort4 o;
        o.x = f2bf(tile[kc+0][n]); o.y = f2bf(tile[kc+1][n]);
        o.z = f2bf(tile[kc+2][n]); o.w = f2bf(tile[kc+3][n]);
        *(ushort4*)(out + (size_t)(n0 + n) * HIDDEN + k0 + kc) = o;
    }
}

// ---------------------------------------------------------------------------
// Projection GEMM: A f32 [8192][1024] x Wt bf16 [1024][1024] (n-major)
// out: bf16 head-split [B*H][T][D], value scaled by `scale`
// 128x128 tile, 4 waves (2x2), BK=32, row pad to 40 bf16 (80B: 16B-aligned)
// ---------------------------------------------------------------------------
#define LP 40

__global__ __launch_bounds__(256) void proj_gemm(const float* __restrict__ A,
                                                 const unsigned short* __restrict__ Bt,
                                                 unsigned short* __restrict__ out,
                                                 float scale) {
    __shared__ alignas(16) unsigned short As[128 * LP];
    __shared__ alignas(16) unsigned short Bs[128 * LP];
    int t = threadIdx.x;
    int wave = t >> 6, lane = t & 63;
    int wr = wave >> 1, wc = wave & 1;
    int lr = lane & 15, lg = lane >> 4;
    int m0 = blockIdx.y * 128, n0 = blockIdx.x * 128;
    f32x4 acc[4][4] = {};

    for (int k0 = 0; k0 < HIDDEN; k0 += 32) {
        __syncthreads();
        // stage A (f32 -> bf16)
#pragma unroll
        for (int i = 0; i < 4; i++) {
            int c = i * 256 + t;
            int row = c >> 3, col4 = (c & 7) * 4;
            float4 v = *(const float4*)(A + (size_t)(m0 + row) * HIDDEN + k0 + col4);
            ushort4 o; o.x = f2bf(v.x); o.y = f2bf(v.y); o.z = f2bf(v.z); o.w = f2bf(v.w);
            *(ushort4*)(&As[row * LP + col4]) = o;
        }
        // stage B (bf16 16B chunks)
#pragma unroll
        for (int i = 0; i < 2; i++) {
            int c = i * 256 + t;
            int row = c >> 2, col8 = (c & 3) * 8;
            uint4 v = *(const uint4*)(Bt + (size_t)(n0 + row) * HIDDEN + k0 + col8);
            *(uint4*)(&Bs[row * LP + col8]) = v;
        }
        __syncthreads();
        s16x8 af[4], bfr[4];
#pragma unroll
        for (int mi = 0; mi < 4; mi++)
            af[mi] = *(const s16x8*)(&As[(wr * 64 + mi * 16 + lr) * LP + lg * 8]);
#pragma unroll
        for (int ni = 0; ni < 4; ni++)
            bfr[ni] = *(const s16x8*)(&Bs[(wc * 64 + ni * 16 + lr) * LP + lg * 8]);
#pragma unroll
        for (int mi = 0; mi < 4; mi++)
#pragma unroll
            for (int ni = 0; ni < 4; ni++)
                acc[mi][ni] = __builtin_amdgcn_mfma_f32_16x16x32_bf16(af[mi], bfr[ni], acc[mi][ni], 0, 0, 0);
    }
    // write head-split bf16: out[(b*NH+h)][t][d]
#pragma unroll
    for (int mi = 0; mi < 4; mi++)
#pragma unroll
        for (int ni = 0; ni < 4; ni++)
#pragma unroll
            for (int j = 0; j < 4; j++) {
                int m = m0 + wr * 64 + mi * 16 + lg * 4 + j;
                int n = n0 + wc * 64 + ni * 16 + lr;
                int b = m >> 11, tt = m & (TQ - 1);
                int h = n >> 6, d = n & 63;
                out[((size_t)(b * NH + h) * TQ + tt) * DH + d] = f2bf(acc[mi][ni][j] * scale);
            }
}

// ---------------------------------------------------------------------------
// Final GEMM: A bf16 [8192][1024] x Wt bf16 -> out f32 [8192][1024]
// ---------------------------------------------------------------------------
__global__ __launch_bounds__(256) void final_gemm(const unsigned short* __restrict__ A,
                                                  const unsigned short* __restrict__ Bt,
                                                  float* __restrict__ out) {
    __shared__ alignas(16) unsigned short As[128 * LP];
    __shared__ alignas(16) unsigned short Bs[128 * LP];
    int t = threadIdx.x;
    int wave = t >> 6, lane = t & 63;
    int wr = wave >> 1, wc = wave & 1;
    int lr = lane & 15, lg = lane >> 4;
    int m0 = blockIdx.y * 128, n0 = blockIdx.x * 128;
    f32x4 acc[4][4] = {};

    for (int k0 = 0; k0 < HIDDEN; k0 += 32) {
        __syncthreads();
#pragma unroll
        for (int i = 0; i < 2; i++) {
            int c = i * 256 + t;
            int row = c >> 2, col8 = (c & 3) * 8;
            uint4 v = *(const uint4*)(A + (size_t)(m0 + row) * HIDDEN + k0 + col8);
            *(uint4*)(&As[row * LP + col8]) = v;
        }
#pragma unroll
        for (int i = 0; i < 2; i++) {
            int c = i * 256 + t;
            int row = c >> 2, col8 = (c & 3) * 8;
            uint4 v = *(const uint4*)(Bt + (size_t)(n0 + row) * HIDDEN + k0 + col8);
            *(uint4*)(&Bs[row * LP + col8]) = v;
        }
        __syncthreads();
        s16x8 af[4], bfr[4];
#pragma unroll
        for (int mi = 0; mi < 4; mi++)
            af[mi] = *(const s16x8*)(&As[(wr * 64 + mi * 16 + lr) * LP + lg * 8]);
#pragma unroll
        for (int ni = 0; ni < 4; ni++)
            bfr[ni] = *(const s16x8*)(&Bs[(wc * 64 + ni * 16 + lr) * LP + lg * 8]);
#pragma unroll
        for (int mi = 0; mi < 4; mi++)
#pragma unroll
            for (int ni = 0; ni < 4; ni++)
                acc[mi][ni] = __builtin_amdgcn_mfma_f32_16x16x32_bf16(af[mi], bfr[ni], acc[mi][ni], 0, 0, 0);
    }
#pragma unroll
    for (int mi = 0; mi < 4; mi++)
#pragma unroll
        for (int ni = 0; ni < 4; ni++)
#pragma unroll
            for (int j = 0; j < 4; j++) {
                int m = m0 + wr * 64 + mi * 16 + lg * 4 + j;
                int n = n0 + wc * 64 + ni * 16 + lr;
                out[(size_t)m * HIDDEN + n] = acc[mi][ni][j];
            }
}

// ---------------------------------------------------------------------------
// Flash attention: grid (T/64, B*H). 4 waves x 16 q-rows. KV tiles of 64.
// Bias row = pad_mask[bh % NB] (reference's jnp.tile semantics).
// AO written combined-head: [B][T][HID] bf16.
// ---------------------------------------------------------------------------
__global__ __launch_bounds__(256) void attn_kernel(const unsigned short* __restrict__ QP,
                                                   const unsigned short* __restrict__ KP,
                                                   const unsigned short* __restrict__ VP,
                                                   const int* __restrict__ pad_mask,
                                                   unsigned short* __restrict__ AO) {
    __shared__ alignas(16) unsigned short Ks[64 * 72];
    __shared__ alignas(16) unsigned short Vt[64 * 72];
    __shared__ alignas(16) unsigned short Ps[4][16 * 72];
    int t = threadIdx.x, wave = t >> 6, lane = t & 63;
    int lr = lane & 15, lg = lane >> 4;
    int bh = blockIdx.y;
    int q0 = blockIdx.x * 64 + wave * 16;
    const unsigned short* Qb = QP + (size_t)bh * TQ * DH;
    const unsigned short* Kb = KP + (size_t)bh * TQ * DH;
    const unsigned short* Vb = VP + (size_t)bh * TQ * DH;
    const int* mrow = pad_mask + (bh % NB) * TQ;

    s16x8 qf0 = *(const s16x8*)(Qb + (size_t)(q0 + lr) * DH + lg * 8);
    s16x8 qf1 = *(const s16x8*)(Qb + (size_t)(q0 + lr) * DH + 32 + lg * 8);

    f32x4 o[4] = {};
    float mrun[4], lrun[4];
#pragma unroll
    for (int j = 0; j < 4; j++) { mrun[j] = -1e30f; lrun[j] = 0.f; }

    for (int kt = 0; kt < TQ / 64; kt++) {
        __syncthreads();
        // stage K: Ks[key][d]
#pragma unroll
        for (int i = 0; i < 2; i++) {
            int c = i * 256 + t;
            int row = c >> 3, col8 = (c & 7) * 8;
            uint4 v = *(const uint4*)(Kb + (size_t)(kt * 64 + row) * DH + col8);
            *(uint4*)(&Ks[row * 72 + col8]) = v;
        }
        // stage V transposed: Vt[d][key]
#pragma unroll
        for (int i = 0; i < 2; i++) {
            int c = i * 256 + t;
            int row = c >> 3, col8 = (c & 7) * 8;
            uint4 v = *(const uint4*)(Vb + (size_t)(kt * 64 + row) * DH + col8);
            unsigned short* e = (unsigned short*)&v;
#pragma unroll
            for (int j = 0; j < 8; j++) Vt[(col8 + j) * 72 + row] = e[j];
        }
        __syncthreads();
        // S = Q K^T + bias
        f32x4 s[4];
#pragma unroll
        for (int ni = 0; ni < 4; ni++) {
            s16x8 kf0 = *(const s16x8*)(&Ks[(ni * 16 + lr) * 72 + lg * 8]);
            s16x8 kf1 = *(const s16x8*)(&Ks[(ni * 16 + lr) * 72 + 32 + lg * 8]);
            f32x4 z = {};
            z = __builtin_amdgcn_mfma_f32_16x16x32_bf16(qf0, kf0, z, 0, 0, 0);
            z = __builtin_amdgcn_mfma_f32_16x16x32_bf16(qf1, kf1, z, 0, 0, 0);
            int kv = kt * 64 + ni * 16 + lr;
            float bias = mrow[kv] ? -1e9f : 0.f;
#pragma unroll
            for (int j = 0; j < 4; j++) z[j] += bias;
            s[ni] = z;
        }
        // online softmax (rows = lg*4+j, shared across the 16 lanes of each lg group)
#pragma unroll
        for (int j = 0; j < 4; j++) {
            float v = fmaxf(fmaxf(s[0][j], s[1][j]), fmaxf(s[2][j], s[3][j]));
            v = fmaxf(v, __shfl_xor(v, 1));
            v = fmaxf(v, __shfl_xor(v, 2));
            v = fmaxf(v, __shfl_xor(v, 4));
            v = fmaxf(v, __shfl_xor(v, 8));
            float mnew = fmaxf(mrun[j], v);
            float sc = __expf(mrun[j] - mnew);
            mrun[j] = mnew;
            lrun[j] *= sc;
#pragma unroll
            for (int ni = 0; ni < 4; ni++) o[ni][j] *= sc;
            float rs = 0.f;
#pragma unroll
            for (int ni = 0; ni < 4; ni++) {
                float p = __expf(s[ni][j] - mnew);
                s[ni][j] = p;
                rs += p;
            }
            rs += __shfl_xor(rs, 1); rs += __shfl_xor(rs, 2);
            rs += __shfl_xor(rs, 4); rs += __shfl_xor(rs, 8);
            lrun[j] += rs;
        }
        // P -> LDS (bf16), per-wave buffer
        unsigned short* Pw = Ps[wave];
#pragma unroll
        for (int ni = 0; ni < 4; ni++)
#pragma unroll
            for (int j = 0; j < 4; j++)
                Pw[(lg * 4 + j) * 72 + ni * 16 + lr] = f2bf(s[ni][j]);
        // PV
        s16x8 pf0 = *(const s16x8*)(&Pw[lr * 72 + lg * 8]);
        s16x8 pf1 = *(const s16x8*)(&Pw[lr * 72 + 32 + lg * 8]);
#pragma unroll
        for (int ni = 0; ni < 4; ni++) {
            s16x8 vf0 = *(const s16x8*)(&Vt[(ni * 16 + lr) * 72 + lg * 8]);
            s16x8 vf1 = *(const s16x8*)(&Vt[(ni * 16 + lr) * 72 + 32 + lg * 8]);
            o[ni] = __builtin_amdgcn_mfma_f32_16x16x32_bf16(pf0, vf0, o[ni], 0, 0, 0);
            o[ni] = __builtin_amdgcn_mfma_f32_16x16x32_bf16(pf1, vf1, o[ni], 0, 0, 0);
        }
    }
    // normalize + write combined heads [B][T][HID]
    int b = bh >> 4, h = bh & 15;
#pragma unroll
    for (int j = 0; j < 4; j++) {
        float inv = 1.f / lrun[j];
        int tt = q0 + lg * 4 + j;
#pragma unroll
        for (int ni = 0; ni < 4; ni++)
            AO[((size_t)(b * TQ + tt)) * HIDDEN + h * 64 + ni * 16 + lr] = f2bf(o[ni][j] * inv);
    }
}

// ---------------------------------------------------------------------------
extern "C" void kernel_launch(void* const* d_in, const int* in_sizes, int n_in,
                              void* d_out, int out_size, void* d_ws, size_t ws_size,
                              hipStream_t stream) {
    const float* q  = (const float*)d_in[0];
    const float* k  = (const float*)d_in[1];
    const float* v  = (const float*)d_in[2];
    const int* pad  = (const int*)d_in[3];
    const float* Wq = (const float*)d_in[4];
    const float* Wk = (const float*)d_in[5];
    const float* Wv = (const float*)d_in[6];
    const float* Wo = (const float*)d_in[7];
    float* out = (float*)d_out;

    // workspace layout (bf16 elems): Wt 4x1M | QP 8M | KP 8M | VP 8M | AO 8M  => 75.5 MB
    unsigned short* ws = (unsigned short*)d_ws;
    unsigned short* Wt = ws;
    unsigned short* QP = ws + (size_t)4 * 1024 * 1024;
    unsigned short* KP = QP + (size_t)BHN * TQ * DH;
    unsigned short* VP = KP + (size_t)BHN * TQ * DH;
    unsigned short* AO = VP + (size_t)BHN * TQ * DH;
    (void)ws_size; (void)in_sizes; (void)n_in; (void)out_size;

    dim3 b256(256);
    wt_kernel<<<dim3(16, 16, 4), b256, 0, stream>>>(Wq, Wk, Wv, Wo, Wt);
    proj_gemm<<<dim3(8, 64), b256, 0, stream>>>(q, Wt + (size_t)0 * 1024 * 1024, QP, 0.125f);
    proj_gemm<<<dim3(8, 64), b256, 0, stream>>>(k, Wt + (size_t)1 * 1024 * 1024, KP, 1.0f);
    proj_gemm<<<dim3(8, 64), b256, 0, stream>>>(v, Wt + (size_t)2 * 1024 * 1024, VP, 1.0f);
    attn_kernel<<<dim3(TQ / 64, BHN), b256, 0, stream>>>(QP, KP, VP, pad, AO);
    final_gemm<<<dim3(8, 64), b256, 0, stream>>>(AO, Wt + (size_t)3 * 1024 * 1024, out);
}

// Round 2
// 329.155 us; speedup vs baseline: 1.4401x; 1.4401x over previous
//
#include <hip/hip_runtime.h>
#include <hip/hip_bf16.h>

#define TQ 2048
#define HIDDEN 1024
#define NB 4
#define NH 16
#define DH 64
#define BHN (NB*NH)   // 64

typedef __attribute__((ext_vector_type(4))) float f32x4;
typedef __attribute__((ext_vector_type(8))) short s16x8;

__device__ inline unsigned short f2bf(float f) {
    union { float f; unsigned int u; } x; x.f = f;
    unsigned int r = x.u + 0x7fffu + ((x.u >> 16) & 1u);
    return (unsigned short)(r >> 16);
}

// ---------------------------------------------------------------------------
// Weight transpose+convert: Wt[n][k] = bf16(W[k][n]); 4 weights via blockIdx.z
// ---------------------------------------------------------------------------
__global__ __launch_bounds__(256) void wt_kernel(const float* W0, const float* W1,
                                                 const float* W2, const float* W3,
                                                 unsigned short* Wt) {
    const float* W = (blockIdx.z == 0) ? W0 : (blockIdx.z == 1) ? W1
                    : (blockIdx.z == 2) ? W2 : W3;
    unsigned short* out = Wt + (size_t)blockIdx.z * HIDDEN * HIDDEN;
    __shared__ float tile[64][68];
    int t = threadIdx.x;
    int k0 = blockIdx.y * 64, n0 = blockIdx.x * 64;
#pragma unroll
    for (int i = 0; i < 4; i++) {
        int r = (t >> 4) + i * 16;
        int c = (t & 15) * 4;
        float4 v = *(const float4*)(W + (size_t)(k0 + r) * HIDDEN + n0 + c);
        tile[r][c] = v.x; tile[r][c+1] = v.y; tile[r][c+2] = v.z; tile[r][c+3] = v.w;
    }
    __syncthreads();
#pragma unroll
    for (int i = 0; i < 4; i++) {
        int n = (t >> 4) + i * 16;
        int kc = (t & 15) * 4;
        ushort4 o;
        o.x = f2bf(tile[kc+0][n]); o.y = f2bf(tile[kc+1][n]);
        o.z = f2bf(tile[kc+2][n]); o.w = f2bf(tile[kc+3][n]);
        *(ushort4*)(out + (size_t)(n0 + n) * HIDDEN + k0 + kc) = o;
    }
}

// ---------------------------------------------------------------------------
// Projection GEMM: A f32 [8192][1024] x Wt bf16 [1024][1024] (n-major)
// vt=0: out bf16 head-split [B*H][T][D]
// vt=1: out bf16 head-split TRANSPOSED [B*H][D][T]  (for V -> attention B-frags)
// ---------------------------------------------------------------------------
#define LP 40

__global__ __launch_bounds__(256) void proj_gemm(const float* __restrict__ A,
                                                 const unsigned short* __restrict__ Bt,
                                                 unsigned short* __restrict__ out,
                                                 float scale, int vt) {
    __shared__ alignas(16) unsigned short As[128 * LP];
    __shared__ alignas(16) unsigned short Bs[128 * LP];
    int t = threadIdx.x;
    int wave = t >> 6, lane = t & 63;
    int wr = wave >> 1, wc = wave & 1;
    int lr = lane & 15, lg = lane >> 4;
    int m0 = blockIdx.y * 128, n0 = blockIdx.x * 128;
    f32x4 acc[4][4] = {};

    for (int k0 = 0; k0 < HIDDEN; k0 += 32) {
        __syncthreads();
#pragma unroll
        for (int i = 0; i < 4; i++) {
            int c = i * 256 + t;
            int row = c >> 3, col4 = (c & 7) * 4;
            float4 v = *(const float4*)(A + (size_t)(m0 + row) * HIDDEN + k0 + col4);
            ushort4 o; o.x = f2bf(v.x); o.y = f2bf(v.y); o.z = f2bf(v.z); o.w = f2bf(v.w);
            *(ushort4*)(&As[row * LP + col4]) = o;
        }
#pragma unroll
        for (int i = 0; i < 2; i++) {
            int c = i * 256 + t;
            int row = c >> 2, col8 = (c & 3) * 8;
            uint4 v = *(const uint4*)(Bt + (size_t)(n0 + row) * HIDDEN + k0 + col8);
            *(uint4*)(&Bs[row * LP + col8]) = v;
        }
        __syncthreads();
        s16x8 af[4], bfr[4];
#pragma unroll
        for (int mi = 0; mi < 4; mi++)
            af[mi] = *(const s16x8*)(&As[(wr * 64 + mi * 16 + lr) * LP + lg * 8]);
#pragma unroll
        for (int ni = 0; ni < 4; ni++)
            bfr[ni] = *(const s16x8*)(&Bs[(wc * 64 + ni * 16 + lr) * LP + lg * 8]);
#pragma unroll
        for (int mi = 0; mi < 4; mi++)
#pragma unroll
            for (int ni = 0; ni < 4; ni++)
                acc[mi][ni] = __builtin_amdgcn_mfma_f32_16x16x32_bf16(af[mi], bfr[ni], acc[mi][ni], 0, 0, 0);
    }
    if (vt == 0) {
#pragma unroll
        for (int mi = 0; mi < 4; mi++)
#pragma unroll
            for (int ni = 0; ni < 4; ni++)
#pragma unroll
                for (int j = 0; j < 4; j++) {
                    int m = m0 + wr * 64 + mi * 16 + lg * 4 + j;
                    int n = n0 + wc * 64 + ni * 16 + lr;
                    int b = m >> 11, tt = m & (TQ - 1);
                    int h = n >> 6, d = n & 63;
                    out[((size_t)(b * NH + h) * TQ + tt) * DH + d] = f2bf(acc[mi][ni][j] * scale);
                }
    } else {
#pragma unroll
        for (int mi = 0; mi < 4; mi++)
#pragma unroll
            for (int ni = 0; ni < 4; ni++) {
                int m = m0 + wr * 64 + mi * 16 + lg * 4;
                int n = n0 + wc * 64 + ni * 16 + lr;
                int b = m >> 11, tt = m & (TQ - 1);
                int h = n >> 6, d = n & 63;
                ushort4 pk;
                pk.x = f2bf(acc[mi][ni][0] * scale);
                pk.y = f2bf(acc[mi][ni][1] * scale);
                pk.z = f2bf(acc[mi][ni][2] * scale);
                pk.w = f2bf(acc[mi][ni][3] * scale);
                *(ushort4*)(out + ((size_t)(b * NH + h) * DH + d) * TQ + tt) = pk;
            }
    }
}

// ---------------------------------------------------------------------------
// Final GEMM: A bf16 [8192][1024] x Wt bf16 -> out f32 [8192][1024]
// ---------------------------------------------------------------------------
__global__ __launch_bounds__(256) void final_gemm(const unsigned short* __restrict__ A,
                                                  const unsigned short* __restrict__ Bt,
                                                  float* __restrict__ out) {
    __shared__ alignas(16) unsigned short As[128 * LP];
    __shared__ alignas(16) unsigned short Bs[128 * LP];
    int t = threadIdx.x;
    int wave = t >> 6, lane = t & 63;
    int wr = wave >> 1, wc = wave & 1;
    int lr = lane & 15, lg = lane >> 4;
    int m0 = blockIdx.y * 128, n0 = blockIdx.x * 128;
    f32x4 acc[4][4] = {};

    for (int k0 = 0; k0 < HIDDEN; k0 += 32) {
        __syncthreads();
#pragma unroll
        for (int i = 0; i < 2; i++) {
            int c = i * 256 + t;
            int row = c >> 2, col8 = (c & 3) * 8;
            uint4 v = *(const uint4*)(A + (size_t)(m0 + row) * HIDDEN + k0 + col8);
            *(uint4*)(&As[row * LP + col8]) = v;
        }
#pragma unroll
        for (int i = 0; i < 2; i++) {
            int c = i * 256 + t;
            int row = c >> 2, col8 = (c & 3) * 8;
            uint4 v = *(const uint4*)(Bt + (size_t)(n0 + row) * HIDDEN + k0 + col8);
            *(uint4*)(&Bs[row * LP + col8]) = v;
        }
        __syncthreads();
        s16x8 af[4], bfr[4];
#pragma unroll
        for (int mi = 0; mi < 4; mi++)
            af[mi] = *(const s16x8*)(&As[(wr * 64 + mi * 16 + lr) * LP + lg * 8]);
#pragma unroll
        for (int ni = 0; ni < 4; ni++)
            bfr[ni] = *(const s16x8*)(&Bs[(wc * 64 + ni * 16 + lr) * LP + lg * 8]);
#pragma unroll
        for (int mi = 0; mi < 4; mi++)
#pragma unroll
            for (int ni = 0; ni < 4; ni++)
                acc[mi][ni] = __builtin_amdgcn_mfma_f32_16x16x32_bf16(af[mi], bfr[ni], acc[mi][ni], 0, 0, 0);
    }
#pragma unroll
    for (int mi = 0; mi < 4; mi++)
#pragma unroll
        for (int ni = 0; ni < 4; ni++)
#pragma unroll
            for (int j = 0; j < 4; j++) {
                int m = m0 + wr * 64 + mi * 16 + lg * 4 + j;
                int n = n0 + wc * 64 + ni * 16 + lr;
                out[(size_t)m * HIDDEN + n] = acc[mi][ni][j];
            }
}

// ---------------------------------------------------------------------------
// Flash attention, swapped-QK structure.
// grid (T/128, B*H); 4 waves x 32 q-rows (2 subtiles of 16). KV tiles of 64.
// S^T = mfma(K_frag, Q_frag): lane holds q=lane&15, k = ni*16 + lg*4 + r.
// Softmax: in-lane 16-reduce + shfl_xor(16,32). P -> LDS as b64 dword pairs.
// V comes pre-transposed from proj (VT[bh][d][t]) -> conflict-free B-frags.
// ---------------------------------------------------------------------------
__global__ __launch_bounds__(256, 4) void attn_kernel(const unsigned short* __restrict__ QP,
                                                      const unsigned short* __restrict__ KP,
                                                      const unsigned short* __restrict__ VT,
                                                      const int* __restrict__ pad_mask,
                                                      unsigned short* __restrict__ AO) {
    __shared__ alignas(16) unsigned short Ks[64 * 72];
    __shared__ alignas(16) unsigned short Vs[64 * 72];
    __shared__ alignas(16) unsigned short Ps[4][2][16 * 72];
    __shared__ float bias_s[64];
    int t = threadIdx.x, wave = t >> 6, lane = t & 63;
    int lr = lane & 15, lg = lane >> 4;
    int bh = blockIdx.y;
    int q0 = blockIdx.x * 128 + wave * 32;
    const unsigned short* Qb = QP + (size_t)bh * TQ * DH;
    const unsigned short* Kb = KP + (size_t)bh * TQ * DH;
    const unsigned short* Vb = VT + (size_t)bh * DH * TQ;
    const int* mrow = pad_mask + (bh & (NB - 1)) * TQ;  // (b*H+h)%B == h%4

    s16x8 qf[2][2];
#pragma unroll
    for (int u = 0; u < 2; u++)
#pragma unroll
        for (int h = 0; h < 2; h++)
            qf[u][h] = *(const s16x8*)(Qb + (size_t)(q0 + u * 16 + lr) * DH + h * 32 + lg * 8);

    f32x4 o[2][4] = {};
    float mrun[2] = {-1e30f, -1e30f};
    float lrun[2] = {0.f, 0.f};

    for (int kt = 0; kt < TQ / 64; kt++) {
        __syncthreads();
        // stage K tile [64 keys][64 d]
#pragma unroll
        for (int i = 0; i < 2; i++) {
            int c = i * 256 + t;
            int row = c >> 3, col8 = (c & 7) * 8;
            *(uint4*)(&Ks[row * 72 + col8]) =
                *(const uint4*)(Kb + (size_t)(kt * 64 + row) * DH + col8);
        }
        // stage V tile [64 d][64 keys] from pre-transposed VT (coalesced)
#pragma unroll
        for (int i = 0; i < 2; i++) {
            int c = i * 256 + t;
            int row = c >> 3, col8 = (c & 7) * 8;
            *(uint4*)(&Vs[row * 72 + col8]) =
                *(const uint4*)(Vb + (size_t)row * TQ + kt * 64 + col8);
        }
        // stage additive bias for this key tile
        if (t < 16) {
            int4 mm = *(const int4*)(mrow + kt * 64 + t * 4);
            bias_s[t * 4 + 0] = (float)mm.x * -1e9f;
            bias_s[t * 4 + 1] = (float)mm.y * -1e9f;
            bias_s[t * 4 + 2] = (float)mm.z * -1e9f;
            bias_s[t * 4 + 3] = (float)mm.w * -1e9f;
        }
        __syncthreads();

#pragma unroll
        for (int u = 0; u < 2; u++) {
            // S^T: lane q=lr, k = ni*16 + lg*4 + r
            f32x4 s[4];
#pragma unroll
            for (int ni = 0; ni < 4; ni++) {
                s16x8 kf0 = *(const s16x8*)(&Ks[(ni * 16 + lr) * 72 + lg * 8]);
                s16x8 kf1 = *(const s16x8*)(&Ks[(ni * 16 + lr) * 72 + 32 + lg * 8]);
                f32x4 z = {};
                z = __builtin_amdgcn_mfma_f32_16x16x32_bf16(kf0, qf[u][0], z, 0, 0, 0);
                z = __builtin_amdgcn_mfma_f32_16x16x32_bf16(kf1, qf[u][1], z, 0, 0, 0);
                float4 bv = *(const float4*)(&bias_s[ni * 16 + lg * 4]);
                z[0] += bv.x; z[1] += bv.y; z[2] += bv.z; z[3] += bv.w;
                s[ni] = z;
            }
            // online softmax: in-lane 16-max, then combine lg groups
            float vm = fmaxf(fmaxf(fmaxf(s[0][0], s[0][1]), fmaxf(s[0][2], s[0][3])),
                             fmaxf(fmaxf(s[1][0], s[1][1]), fmaxf(s[1][2], s[1][3])));
            vm = fmaxf(vm, fmaxf(fmaxf(fmaxf(s[2][0], s[2][1]), fmaxf(s[2][2], s[2][3])),
                                 fmaxf(fmaxf(s[3][0], s[3][1]), fmaxf(s[3][2], s[3][3]))));
            vm = fmaxf(vm, __shfl_xor(vm, 16));
            vm = fmaxf(vm, __shfl_xor(vm, 32));
            float mnew = fmaxf(mrun[u], vm);
            float sc = __expf(mrun[u] - mnew);
            mrun[u] = mnew;
            float rs = 0.f;
#pragma unroll
            for (int ni = 0; ni < 4; ni++)
#pragma unroll
                for (int r = 0; r < 4; r++) {
                    float p = __expf(s[ni][r] - mnew);
                    s[ni][r] = p;
                    rs += p;
                }
            rs += __shfl_xor(rs, 16);
            rs += __shfl_xor(rs, 32);
            lrun[u] = lrun[u] * sc + rs;
            // rescale O (rows q = lg*4+r need sc from lane lg*4+r)
            float scr[4];
#pragma unroll
            for (int r = 0; r < 4; r++) scr[r] = __shfl(sc, lg * 4 + r);
#pragma unroll
            for (int di = 0; di < 4; di++)
#pragma unroll
                for (int r = 0; r < 4; r++) o[u][di][r] *= scr[r];
            // P -> LDS (bf16), b64 stores contiguous along k
            unsigned short* Pw = Ps[wave][u];
#pragma unroll
            for (int ni = 0; ni < 4; ni++) {
                uint2 w;
                w.x = (unsigned int)f2bf(s[ni][0]) | ((unsigned int)f2bf(s[ni][1]) << 16);
                w.y = (unsigned int)f2bf(s[ni][2]) | ((unsigned int)f2bf(s[ni][3]) << 16);
                *(uint2*)(&Pw[lr * 72 + ni * 16 + lg * 4]) = w;
            }
            // PV: A = P[q][k] frags, B = V[k][d] frags from Vs (conflict-free)
            s16x8 pa0 = *(const s16x8*)(&Pw[lr * 72 + lg * 8]);
            s16x8 pa1 = *(const s16x8*)(&Pw[lr * 72 + 32 + lg * 8]);
#pragma unroll
            for (int di = 0; di < 4; di++) {
                s16x8 vf0 = *(const s16x8*)(&Vs[(di * 16 + lr) * 72 + lg * 8]);
                s16x8 vf1 = *(const s16x8*)(&Vs[(di * 16 + lr) * 72 + 32 + lg * 8]);
                o[u][di] = __builtin_amdgcn_mfma_f32_16x16x32_bf16(pa0, vf0, o[u][di], 0, 0, 0);
                o[u][di] = __builtin_amdgcn_mfma_f32_16x16x32_bf16(pa1, vf1, o[u][di], 0, 0, 0);
            }
        }
    }
    // epilogue: normalize, write combined heads [B][T][HID]
    int b = bh >> 4, h = bh & 15;
#pragma unroll
    for (int u = 0; u < 2; u++) {
        float li[4];
#pragma unroll
        for (int r = 0; r < 4; r++) li[r] = 1.f / __shfl(lrun[u], lg * 4 + r);
#pragma unroll
        for (int r = 0; r < 4; r++) {
            int tt = q0 + u * 16 + lg * 4 + r;
#pragma unroll
            for (int di = 0; di < 4; di++)
                AO[((size_t)(b * TQ + tt)) * HIDDEN + h * 64 + di * 16 + lr] =
                    f2bf(o[u][di][r] * li[r]);
        }
    }
}

// ---------------------------------------------------------------------------
extern "C" void kernel_launch(void* const* d_in, const int* in_sizes, int n_in,
                              void* d_out, int out_size, void* d_ws, size_t ws_size,
                              hipStream_t stream) {
    const float* q  = (const float*)d_in[0];
    const float* k  = (const float*)d_in[1];
    const float* v  = (const float*)d_in[2];
    const int* pad  = (const int*)d_in[3];
    const float* Wq = (const float*)d_in[4];
    const float* Wk = (const float*)d_in[5];
    const float* Wv = (const float*)d_in[6];
    const float* Wo = (const float*)d_in[7];
    float* out = (float*)d_out;

    // workspace (bf16 elems): Wt 4x1M | QP 8M | KP 8M | VT 8M | AO 8M
    unsigned short* ws = (unsigned short*)d_ws;
    unsigned short* Wt = ws;
    unsigned short* QP = ws + (size_t)4 * 1024 * 1024;
    unsigned short* KP = QP + (size_t)BHN * TQ * DH;
    unsigned short* VTb = KP + (size_t)BHN * TQ * DH;
    unsigned short* AO = VTb + (size_t)BHN * TQ * DH;
    (void)ws_size; (void)in_sizes; (void)n_in; (void)out_size;

    dim3 b256(256);
    wt_kernel<<<dim3(16, 16, 4), b256, 0, stream>>>(Wq, Wk, Wv, Wo, Wt);
    proj_gemm<<<dim3(8, 64), b256, 0, stream>>>(q, Wt + (size_t)0 * 1024 * 1024, QP, 0.125f, 0);
    proj_gemm<<<dim3(8, 64), b256, 0, stream>>>(k, Wt + (size_t)1 * 1024 * 1024, KP, 1.0f, 0);
    proj_gemm<<<dim3(8, 64), b256, 0, stream>>>(v, Wt + (size_t)2 * 1024 * 1024, VTb, 1.0f, 1);
    attn_kernel<<<dim3(TQ / 128, BHN), b256, 0, stream>>>(QP, KP, VTb, pad, AO);
    final_gemm<<<dim3(8, 64), b256, 0, stream>>>(AO, Wt + (size_t)3 * 1024 * 1024, out);
}

// Round 4
// 325.672 us; speedup vs baseline: 1.4555x; 1.0107x over previous
//
#include <hip/hip_runtime.h>
#include <hip/hip_bf16.h>

#define TQ 2048
#define HIDDEN 1024
#define NB 4
#define NH 16
#define DH 64
#define BHN (NB*NH)   // 64
#define LOG2E 1.44269504f

typedef __attribute__((ext_vector_type(4))) float f32x4;
typedef __attribute__((ext_vector_type(8))) short s16x8;

__device__ inline unsigned short f2bf(float f) {
    union { float f; unsigned int u; } x; x.f = f;
    unsigned int r = x.u + 0x7fffu + ((x.u >> 16) & 1u);
    return (unsigned short)(r >> 16);
}

__device__ inline unsigned int pkbf(float a, float b) {
    __hip_bfloat162 h = __float22bfloat162_rn(make_float2(a, b));
    return *reinterpret_cast<unsigned int*>(&h);
}

union PBU { uint4 u4; s16x8 v; };

// ---------------------------------------------------------------------------
// pad_mask -> float bias row (log2 domain): biasF[i] = mask[i] * (-1e9*log2e)
// ---------------------------------------------------------------------------
__global__ __launch_bounds__(256) void maskf_kernel(const int* __restrict__ pad,
                                                    float* __restrict__ biasF) {
    int i = blockIdx.x * 256 + threadIdx.x;
    biasF[i] = (float)pad[i] * (-1.44269504e9f);
}

// ---------------------------------------------------------------------------
// Weight transpose+convert: Wt[n][k] = bf16(W[k][n]); 4 weights via blockIdx.z
// ---------------------------------------------------------------------------
__global__ __launch_bounds__(256) void wt_kernel(const float* W0, const float* W1,
                                                 const float* W2, const float* W3,
                                                 unsigned short* Wt) {
    const float* W = (blockIdx.z == 0) ? W0 : (blockIdx.z == 1) ? W1
                    : (blockIdx.z == 2) ? W2 : W3;
    unsigned short* out = Wt + (size_t)blockIdx.z * HIDDEN * HIDDEN;
    __shared__ float tile[64][68];
    int t = threadIdx.x;
    int k0 = blockIdx.y * 64, n0 = blockIdx.x * 64;
#pragma unroll
    for (int i = 0; i < 4; i++) {
        int r = (t >> 4) + i * 16;
        int c = (t & 15) * 4;
        float4 v = *(const float4*)(W + (size_t)(k0 + r) * HIDDEN + n0 + c);
        tile[r][c] = v.x; tile[r][c+1] = v.y; tile[r][c+2] = v.z; tile[r][c+3] = v.w;
    }
    __syncthreads();
#pragma unroll
    for (int i = 0; i < 4; i++) {
        int n = (t >> 4) + i * 16;
        int kc = (t & 15) * 4;
        ushort4 o;
        o.x = f2bf(tile[kc+0][n]); o.y = f2bf(tile[kc+1][n]);
        o.z = f2bf(tile[kc+2][n]); o.w = f2bf(tile[kc+3][n]);
        *(ushort4*)(out + (size_t)(n0 + n) * HIDDEN + k0 + kc) = o;
    }
}

// ---------------------------------------------------------------------------
// Projection GEMM: A f32 [8192][1024] x Wt bf16 [1024][1024] (n-major)
// vt=0: out bf16 head-split [B*H][T][D]
// vt=1: out bf16 head-split TRANSPOSED [B*H][D][T]
// ---------------------------------------------------------------------------
#define LP 40

__global__ __launch_bounds__(256) void proj_gemm(const float* __restrict__ A,
                                                 const unsigned short* __restrict__ Bt,
                                                 unsigned short* __restrict__ out,
                                                 float scale, int vt) {
    __shared__ alignas(16) unsigned short As[128 * LP];
    __shared__ alignas(16) unsigned short Bs[128 * LP];
    int t = threadIdx.x;
    int wave = t >> 6, lane = t & 63;
    int wr = wave >> 1, wc = wave & 1;
    int lr = lane & 15, lg = lane >> 4;
    int m0 = blockIdx.y * 128, n0 = blockIdx.x * 128;
    f32x4 acc[4][4] = {};

    for (int k0 = 0; k0 < HIDDEN; k0 += 32) {
        __syncthreads();
#pragma unroll
        for (int i = 0; i < 4; i++) {
            int c = i * 256 + t;
            int row = c >> 3, col4 = (c & 7) * 4;
            float4 v = *(const float4*)(A + (size_t)(m0 + row) * HIDDEN + k0 + col4);
            ushort4 o; o.x = f2bf(v.x); o.y = f2bf(v.y); o.z = f2bf(v.z); o.w = f2bf(v.w);
            *(ushort4*)(&As[row * LP + col4]) = o;
        }
#pragma unroll
        for (int i = 0; i < 2; i++) {
            int c = i * 256 + t;
            int row = c >> 2, col8 = (c & 3) * 8;
            uint4 v = *(const uint4*)(Bt + (size_t)(n0 + row) * HIDDEN + k0 + col8);
            *(uint4*)(&Bs[row * LP + col8]) = v;
        }
        __syncthreads();
        s16x8 af[4], bfr[4];
#pragma unroll
        for (int mi = 0; mi < 4; mi++)
            af[mi] = *(const s16x8*)(&As[(wr * 64 + mi * 16 + lr) * LP + lg * 8]);
#pragma unroll
        for (int ni = 0; ni < 4; ni++)
            bfr[ni] = *(const s16x8*)(&Bs[(wc * 64 + ni * 16 + lr) * LP + lg * 8]);
#pragma unroll
        for (int mi = 0; mi < 4; mi++)
#pragma unroll
            for (int ni = 0; ni < 4; ni++)
                acc[mi][ni] = __builtin_amdgcn_mfma_f32_16x16x32_bf16(af[mi], bfr[ni], acc[mi][ni], 0, 0, 0);
    }
    if (vt == 0) {
#pragma unroll
        for (int mi = 0; mi < 4; mi++)
#pragma unroll
            for (int ni = 0; ni < 4; ni++)
#pragma unroll
                for (int j = 0; j < 4; j++) {
                    int m = m0 + wr * 64 + mi * 16 + lg * 4 + j;
                    int n = n0 + wc * 64 + ni * 16 + lr;
                    int b = m >> 11, tt = m & (TQ - 1);
                    int h = n >> 6, d = n & 63;
                    out[((size_t)(b * NH + h) * TQ + tt) * DH + d] = f2bf(acc[mi][ni][j] * scale);
                }
    } else {
#pragma unroll
        for (int mi = 0; mi < 4; mi++)
#pragma unroll
            for (int ni = 0; ni < 4; ni++) {
                int m = m0 + wr * 64 + mi * 16 + lg * 4;
                int n = n0 + wc * 64 + ni * 16 + lr;
                int b = m >> 11, tt = m & (TQ - 1);
                int h = n >> 6, d = n & 63;
                ushort4 pk;
                pk.x = f2bf(acc[mi][ni][0] * scale);
                pk.y = f2bf(acc[mi][ni][1] * scale);
                pk.z = f2bf(acc[mi][ni][2] * scale);
                pk.w = f2bf(acc[mi][ni][3] * scale);
                *(ushort4*)(out + ((size_t)(b * NH + h) * DH + d) * TQ + tt) = pk;
            }
    }
}

// ---------------------------------------------------------------------------
// Final GEMM: A bf16 [8192][1024] x Wt bf16 -> out f32 [8192][1024]
// ---------------------------------------------------------------------------
__global__ __launch_bounds__(256) void final_gemm(const unsigned short* __restrict__ A,
                                                  const unsigned short* __restrict__ Bt,
                                                  float* __restrict__ out) {
    __shared__ alignas(16) unsigned short As[128 * LP];
    __shared__ alignas(16) unsigned short Bs[128 * LP];
    int t = threadIdx.x;
    int wave = t >> 6, lane = t & 63;
    int wr = wave >> 1, wc = wave & 1;
    int lr = lane & 15, lg = lane >> 4;
    int m0 = blockIdx.y * 128, n0 = blockIdx.x * 128;
    f32x4 acc[4][4] = {};

    for (int k0 = 0; k0 < HIDDEN; k0 += 32) {
        __syncthreads();
#pragma unroll
        for (int i = 0; i < 2; i++) {
            int c = i * 256 + t;
            int row = c >> 2, col8 = (c & 3) * 8;
            uint4 v = *(const uint4*)(A + (size_t)(m0 + row) * HIDDEN + k0 + col8);
            *(uint4*)(&As[row * LP + col8]) = v;
        }
#pragma unroll
        for (int i = 0; i < 2; i++) {
            int c = i * 256 + t;
            int row = c >> 2, col8 = (c & 3) * 8;
            uint4 v = *(const uint4*)(Bt + (size_t)(n0 + row) * HIDDEN + k0 + col8);
            *(uint4*)(&Bs[row * LP + col8]) = v;
        }
        __syncthreads();
        s16x8 af[4], bfr[4];
#pragma unroll
        for (int mi = 0; mi < 4; mi++)
            af[mi] = *(const s16x8*)(&As[(wr * 64 + mi * 16 + lr) * LP + lg * 8]);
#pragma unroll
        for (int ni = 0; ni < 4; ni++)
            bfr[ni] = *(const s16x8*)(&Bs[(wc * 64 + ni * 16 + lr) * LP + lg * 8]);
#pragma unroll
        for (int mi = 0; mi < 4; mi++)
#pragma unroll
            for (int ni = 0; ni < 4; ni++)
                acc[mi][ni] = __builtin_amdgcn_mfma_f32_16x16x32_bf16(af[mi], bfr[ni], acc[mi][ni], 0, 0, 0);
    }
#pragma unroll
    for (int mi = 0; mi < 4; mi++)
#pragma unroll
        for (int ni = 0; ni < 4; ni++)
#pragma unroll
            for (int j = 0; j < 4; j++) {
                int m = m0 + wr * 64 + mi * 16 + lg * 4 + j;
                int n = n0 + wc * 64 + ni * 16 + lr;
                out[(size_t)m * HIDDEN + n] = acc[mi][ni][j];
            }
}

// ---------------------------------------------------------------------------
// Flash attention v3.
// grid (T/128, B*H); 4 waves x 32 q-rows. KV tiles of 64, double-buffered LDS,
// reg-staged (1 barrier/tile). Swapped QK (S^T, q=lane&15). PV computed as
// O^T = mfma(A=V^T frag, B=P^T frag) with a global k-slot permutation
// (k = ks*32+ni'*16+lg*4+r  <->  slot ks*32+lg*8+ni'*4+r) so the P B-frag is
// built fully in-lane from the S registers (8 cvt_pk, no LDS, no shuffles).
// V staged with the matching 8B-group column permutation. Softmax in log2
// domain (log2e folded into Q scale and bias), defer-max THR=8.
// ---------------------------------------------------------------------------
__global__ __launch_bounds__(256, 3) void attn_kernel(
        const unsigned short* __restrict__ QP,
        const unsigned short* __restrict__ KP,
        const unsigned short* __restrict__ VT,
        const float* __restrict__ biasF,
        unsigned short* __restrict__ AO) {
    __shared__ alignas(16) unsigned short Ks[2][64 * 72];
    __shared__ alignas(16) unsigned short Vs[2][64 * 72];
    const int t = threadIdx.x, wave = t >> 6, lane = t & 63;
    const int lr = lane & 15, lg = lane >> 4;
    const int bh = blockIdx.y;
    const int q0 = blockIdx.x * 128 + wave * 32;
    const unsigned short* Qb = QP + (size_t)bh * TQ * DH;
    const unsigned short* Kb = KP + (size_t)bh * TQ * DH;
    const unsigned short* Vb = VT + (size_t)bh * DH * TQ;
    const float* biasRow = biasF + (bh & (NB - 1)) * TQ;

    // Q fragments (Q pre-scaled by D^-0.5 * log2e in projection)
    s16x8 qf[2][2];
#pragma unroll
    for (int u = 0; u < 2; u++)
#pragma unroll
        for (int h = 0; h < 2; h++)
            qf[u][h] = *(const s16x8*)(Qb + (size_t)(q0 + u * 16 + lr) * DH + h * 32 + lg * 8);

    // staging geometry (fixed per thread)
    const int c0 = t, c1 = 256 + t;
    const int sr0 = c0 >> 3, scl0 = (c0 & 7) * 8;
    const int sr1 = c1 >> 3, scl1 = (c1 & 7) * 8;
    const unsigned short* kA0 = Kb + sr0 * DH + scl0;
    const unsigned short* kA1 = Kb + sr1 * DH + scl1;
    const unsigned short* vA0 = Vb + (size_t)sr0 * TQ + scl0;
    const unsigned short* vA1 = Vb + (size_t)sr1 * TQ + scl1;
    const int ksO0 = sr0 * 72 + scl0, ksO1 = sr1 * 72 + scl1;
    const int cc0 = c0 & 7, cc1 = c1 & 7;
    const int vg0 = ((cc0 & 4) << 1) + ((cc0 & 1) << 2) + ((cc0 >> 1) & 1);
    const int vg1 = ((cc1 & 4) << 1) + ((cc1 & 1) << 2) + ((cc1 >> 1) & 1);
    const int vO0 = sr0 * 72 + vg0 * 4, vO1 = sr1 * 72 + vg1 * 4;

    uint4 kr0, kr1, vr0, vr1;
#define LOAD_TILE(kt_) do { \
        kr0 = *(const uint4*)(kA0 + (size_t)(kt_) * 4096); \
        kr1 = *(const uint4*)(kA1 + (size_t)(kt_) * 4096); \
        vr0 = *(const uint4*)(vA0 + (size_t)(kt_) * 64); \
        vr1 = *(const uint4*)(vA1 + (size_t)(kt_) * 64); \
    } while (0)
#define STORE_TILE(b_) do { \
        *(uint4*)(&Ks[b_][ksO0]) = kr0; \
        *(uint4*)(&Ks[b_][ksO1]) = kr1; \
        *(uint2*)(&Vs[b_][vO0])     = make_uint2(vr0.x, vr0.y); \
        *(uint2*)(&Vs[b_][vO0 + 8]) = make_uint2(vr0.z, vr0.w); \
        *(uint2*)(&Vs[b_][vO1])     = make_uint2(vr1.x, vr1.y); \
        *(uint2*)(&Vs[b_][vO1 + 8]) = make_uint2(vr1.z, vr1.w); \
    } while (0)

    f32x4 o[2][4] = {};
    float mrun[2] = {-1e30f, -1e30f};
    float lrun[2] = {0.f, 0.f};

    LOAD_TILE(0);
    STORE_TILE(0);

    const int NT = TQ / 64;
    for (int kt = 0; kt < NT; kt++) {
        __syncthreads();
        const int cur = kt & 1;
        if (kt + 1 < NT) LOAD_TILE(kt + 1);

        // bias (log2 domain), k = kt*64 + ni*16 + lg*4 + r
        float4 bb[4];
#pragma unroll
        for (int ni = 0; ni < 4; ni++)
            bb[ni] = *(const float4*)(biasRow + kt * 64 + ni * 16 + lg * 4);

        // S^T for both q-subtiles: z[u][ni][r], q=lr, k=ni*16+lg*4+r
        f32x4 z[2][4] = {};
#pragma unroll
        for (int ni = 0; ni < 4; ni++) {
            s16x8 kf0 = *(const s16x8*)(&Ks[cur][(ni * 16 + lr) * 72 + lg * 8]);
            s16x8 kf1 = *(const s16x8*)(&Ks[cur][(ni * 16 + lr) * 72 + 32 + lg * 8]);
#pragma unroll
            for (int u = 0; u < 2; u++) {
                z[u][ni] = __builtin_amdgcn_mfma_f32_16x16x32_bf16(kf0, qf[u][0], z[u][ni], 0, 0, 0);
                z[u][ni] = __builtin_amdgcn_mfma_f32_16x16x32_bf16(kf1, qf[u][1], z[u][ni], 0, 0, 0);
            }
        }

        PBU pb[2][2];
#pragma unroll
        for (int u = 0; u < 2; u++) {
#pragma unroll
            for (int ni = 0; ni < 4; ni++) {
                z[u][ni][0] += bb[ni].x; z[u][ni][1] += bb[ni].y;
                z[u][ni][2] += bb[ni].z; z[u][ni][3] += bb[ni].w;
            }
            // row max (16 in-lane + combine 4 lg groups)
            float vm = fmaxf(fmaxf(fmaxf(z[u][0][0], z[u][0][1]), fmaxf(z[u][0][2], z[u][0][3])),
                             fmaxf(fmaxf(z[u][1][0], z[u][1][1]), fmaxf(z[u][1][2], z[u][1][3])));
            vm = fmaxf(vm, fmaxf(fmaxf(fmaxf(z[u][2][0], z[u][2][1]), fmaxf(z[u][2][2], z[u][2][3])),
                                 fmaxf(fmaxf(z[u][3][0], z[u][3][1]), fmaxf(z[u][3][2], z[u][3][3]))));
            vm = fmaxf(vm, __shfl_xor(vm, 16));
            vm = fmaxf(vm, __shfl_xor(vm, 32));
            // defer-max: rescale only if some row max grew past THR
            if (__any(vm > mrun[u] + 8.f)) {
                float mnew = fmaxf(mrun[u], vm);
                float sc = exp2f(mrun[u] - mnew);
                mrun[u] = mnew;
                lrun[u] *= sc;
#pragma unroll
                for (int di = 0; di < 4; di++) {
                    o[u][di][0] *= sc; o[u][di][1] *= sc;
                    o[u][di][2] *= sc; o[u][di][3] *= sc;
                }
            }
            const float m = mrun[u];
            float rs = 0.f;
#pragma unroll
            for (int ni = 0; ni < 4; ni++)
#pragma unroll
                for (int r = 0; r < 4; r++) {
                    float p = exp2f(z[u][ni][r] - m);
                    z[u][ni][r] = p;
                    rs += p;
                }
            rs += __shfl_xor(rs, 16);
            rs += __shfl_xor(rs, 32);
            lrun[u] += rs;
            // pack P^T B-frags fully in-lane (k-slot permutation)
#pragma unroll
            for (int ks = 0; ks < 2; ks++) {
                pb[u][ks].u4.x = pkbf(z[u][2 * ks][0], z[u][2 * ks][1]);
                pb[u][ks].u4.y = pkbf(z[u][2 * ks][2], z[u][2 * ks][3]);
                pb[u][ks].u4.z = pkbf(z[u][2 * ks + 1][0], z[u][2 * ks + 1][1]);
                pb[u][ks].u4.w = pkbf(z[u][2 * ks + 1][2], z[u][2 * ks + 1][3]);
            }
        }

        // O^T += V^T x P^T  (Vs is kappa-permuted to match pb's slot order)
#pragma unroll
        for (int di = 0; di < 4; di++)
#pragma unroll
            for (int ks = 0; ks < 2; ks++) {
                s16x8 vf = *(const s16x8*)(&Vs[cur][(di * 16 + lr) * 72 + ks * 32 + lg * 8]);
#pragma unroll
                for (int u = 0; u < 2; u++)
                    o[u][di] = __builtin_amdgcn_mfma_f32_16x16x32_bf16(vf, pb[u][ks].v, o[u][di], 0, 0, 0);
            }

        if (kt + 1 < NT) STORE_TILE((kt + 1) & 1);
    }

    // epilogue: O^T lane holds q=lr, d=di*16+lg*4+r; shuffle-free normalize
    const int b = bh >> 4, h = bh & 15;
#pragma unroll
    for (int u = 0; u < 2; u++) {
        float inv = 1.f / lrun[u];
        int tt = q0 + u * 16 + lr;
#pragma unroll
        for (int di = 0; di < 4; di++) {
            uint2 w;
            w.x = pkbf(o[u][di][0] * inv, o[u][di][1] * inv);
            w.y = pkbf(o[u][di][2] * inv, o[u][di][3] * inv);
            *(uint2*)(AO + (size_t)(b * TQ + tt) * HIDDEN + h * 64 + di * 16 + lg * 4) = w;
        }
    }
#undef LOAD_TILE
#undef STORE_TILE
}

// ---------------------------------------------------------------------------
extern "C" void kernel_launch(void* const* d_in, const int* in_sizes, int n_in,
                              void* d_out, int out_size, void* d_ws, size_t ws_size,
                              hipStream_t stream) {
    const float* q  = (const float*)d_in[0];
    const float* k  = (const float*)d_in[1];
    const float* v  = (const float*)d_in[2];
    const int* pad  = (const int*)d_in[3];
    const float* Wq = (const float*)d_in[4];
    const float* Wk = (const float*)d_in[5];
    const float* Wv = (const float*)d_in[6];
    const float* Wo = (const float*)d_in[7];
    float* out = (float*)d_out;

    // workspace (bf16 elems): Wt 4x1M | QP 8M | KP 8M | VT 8M | AO 8M | biasF
    unsigned short* ws = (unsigned short*)d_ws;
    unsigned short* Wt = ws;
    unsigned short* QP = ws + (size_t)4 * 1024 * 1024;
    unsigned short* KP = QP + (size_t)BHN * TQ * DH;
    unsigned short* VTb = KP + (size_t)BHN * TQ * DH;
    unsigned short* AO = VTb + (size_t)BHN * TQ * DH;
    float* biasF = (float*)(AO + (size_t)BHN * TQ * DH);
    (void)ws_size; (void)in_sizes; (void)n_in; (void)out_size;

    dim3 b256(256);
    maskf_kernel<<<dim3(NB * TQ / 256), b256, 0, stream>>>(pad, biasF);
    wt_kernel<<<dim3(16, 16, 4), b256, 0, stream>>>(Wq, Wk, Wv, Wo, Wt);
    proj_gemm<<<dim3(8, 64), b256, 0, stream>>>(q, Wt + (size_t)0 * 1024 * 1024, QP, 0.125f * LOG2E, 0);
    proj_gemm<<<dim3(8, 64), b256, 0, stream>>>(k, Wt + (size_t)1 * 1024 * 1024, KP, 1.0f, 0);
    proj_gemm<<<dim3(8, 64), b256, 0, stream>>>(v, Wt + (size_t)2 * 1024 * 1024, VTb, 1.0f, 1);
    attn_kernel<<<dim3(TQ / 128, BHN), b256, 0, stream>>>(QP, KP, VTb, biasF, AO);
    final_gemm<<<dim3(8, 64), b256, 0, stream>>>(AO, Wt + (size_t)3 * 1024 * 1024, out);
}

// Round 5
// 289.464 us; speedup vs baseline: 1.6376x; 1.1251x over previous
//
#include <hip/hip_runtime.h>
#include <hip/hip_bf16.h>

#define TQ 2048
#define HIDDEN 1024
#define NB 4
#define NH 16
#define DH 64
#define BHN (NB*NH)   // 64
#define LOG2E 1.44269504f

typedef __attribute__((ext_vector_type(4))) float f32x4;
typedef __attribute__((ext_vector_type(8))) short s16x8;

__device__ inline unsigned short f2bf(float f) {
    union { float f; unsigned int u; } x; x.f = f;
    unsigned int r = x.u + 0x7fffu + ((x.u >> 16) & 1u);
    return (unsigned short)(r >> 16);
}

__device__ inline unsigned int pkbf(float a, float b) {
    __hip_bfloat162 h = __float22bfloat162_rn(make_float2(a, b));
    return *reinterpret_cast<unsigned int*>(&h);
}

union PBU { uint4 u4; s16x8 v; };

// async global->LDS, 16B per lane; lds dst must be wave-uniform base
#define GLL16(gsrc, ldst) \
    __builtin_amdgcn_global_load_lds( \
        (const __attribute__((address_space(1))) unsigned int*)(gsrc), \
        (__attribute__((address_space(3))) unsigned int*)(ldst), 16, 0, 0)

// ---------------------------------------------------------------------------
// pad_mask -> float bias row (log2 domain)
// ---------------------------------------------------------------------------
__global__ __launch_bounds__(256) void maskf_kernel(const int* __restrict__ pad,
                                                    float* __restrict__ biasF) {
    int i = blockIdx.x * 256 + threadIdx.x;
    biasF[i] = (float)pad[i] * (-1.44269504e9f);
}

// ---------------------------------------------------------------------------
// f32 -> bf16 convert (8 elems/thread)
// ---------------------------------------------------------------------------
__global__ __launch_bounds__(256) void cvt_kernel(const float* __restrict__ in,
                                                  unsigned short* __restrict__ out) {
    int i = (blockIdx.x * 256 + threadIdx.x) * 8;
    float4 a = *(const float4*)(in + i);
    float4 b = *(const float4*)(in + i + 4);
    uint4 o;
    o.x = pkbf(a.x, a.y); o.y = pkbf(a.z, a.w);
    o.z = pkbf(b.x, b.y); o.w = pkbf(b.z, b.w);
    *(uint4*)(out + i) = o;
}

// ---------------------------------------------------------------------------
// Weight transpose+convert: Wt[n][k] = bf16(W[k][n]); 4 weights via blockIdx.z
// ---------------------------------------------------------------------------
__global__ __launch_bounds__(256) void wt_kernel(const float* W0, const float* W1,
                                                 const float* W2, const float* W3,
                                                 unsigned short* Wt) {
    const float* W = (blockIdx.z == 0) ? W0 : (blockIdx.z == 1) ? W1
                    : (blockIdx.z == 2) ? W2 : W3;
    unsigned short* out = Wt + (size_t)blockIdx.z * HIDDEN * HIDDEN;
    __shared__ float tile[64][68];
    int t = threadIdx.x;
    int k0 = blockIdx.y * 64, n0 = blockIdx.x * 64;
#pragma unroll
    for (int i = 0; i < 4; i++) {
        int r = (t >> 4) + i * 16;
        int c = (t & 15) * 4;
        float4 v = *(const float4*)(W + (size_t)(k0 + r) * HIDDEN + n0 + c);
        tile[r][c] = v.x; tile[r][c+1] = v.y; tile[r][c+2] = v.z; tile[r][c+3] = v.w;
    }
    __syncthreads();
#pragma unroll
    for (int i = 0; i < 4; i++) {
        int n = (t >> 4) + i * 16;
        int kc = (t & 15) * 4;
        ushort4 o;
        o.x = f2bf(tile[kc+0][n]); o.y = f2bf(tile[kc+1][n]);
        o.z = f2bf(tile[kc+2][n]); o.w = f2bf(tile[kc+3][n]);
        *(ushort4*)(out + (size_t)(n0 + n) * HIDDEN + k0 + kc) = o;
    }
}

// ---------------------------------------------------------------------------
// bf16 GEMM core (m97 structure): A bf16 [M][1024] x Bt bf16 [n][k] n-major.
// 128x128 tile, BK=32, linear LDS, both tiles staged via global_load_lds x16.
// vt=0: out bf16 head-split [B*H][T][D], scaled
// vt=1: out bf16 head-split transposed [B*H][D][T], scaled
// vt=2: out f32 [M][1024]
// ---------------------------------------------------------------------------
__global__ __launch_bounds__(256) void gemm_bt(const unsigned short* __restrict__ A,
                                               const unsigned short* __restrict__ Bt,
                                               unsigned short* __restrict__ outb,
                                               float* __restrict__ outf,
                                               float scale, int vt) {
    __shared__ alignas(16) unsigned short As[128 * 32];
    __shared__ alignas(16) unsigned short Bs[128 * 32];
    const int t = threadIdx.x;
    const int wave = t >> 6, lane = t & 63;
    const int wr = wave >> 1, wc = wave & 1;
    const int lr = lane & 15, lg = lane >> 4;
    const int m0 = blockIdx.y * 128, n0 = blockIdx.x * 128;

    // staging: flat 16B chunk index f = c*256+t; row=f>>2, col=(f&3)*8
    const int f0 = t, f1 = 256 + t;
    const size_t gA0 = (size_t)(m0 + (f0 >> 2)) * HIDDEN + (f0 & 3) * 8;
    const size_t gA1 = (size_t)(m0 + (f1 >> 2)) * HIDDEN + (f1 & 3) * 8;
    const size_t gB0 = (size_t)(n0 + (f0 >> 2)) * HIDDEN + (f0 & 3) * 8;
    const size_t gB1 = (size_t)(n0 + (f1 >> 2)) * HIDDEN + (f1 & 3) * 8;
    unsigned short* lA0 = &As[(size_t)(wave * 64) * 8];
    unsigned short* lA1 = &As[(size_t)(256 + wave * 64) * 8];
    unsigned short* lB0 = &Bs[(size_t)(wave * 64) * 8];
    unsigned short* lB1 = &Bs[(size_t)(256 + wave * 64) * 8];

    f32x4 acc[4][4] = {};

    for (int k0 = 0; k0 < HIDDEN; k0 += 32) {
        __syncthreads();
        GLL16(A + gA0 + k0, lA0);
        GLL16(A + gA1 + k0, lA1);
        GLL16(Bt + gB0 + k0, lB0);
        GLL16(Bt + gB1 + k0, lB1);
        __syncthreads();
        s16x8 af[4], bfr[4];
#pragma unroll
        for (int mi = 0; mi < 4; mi++)
            af[mi] = *(const s16x8*)(&As[(wr * 64 + mi * 16 + lr) * 32 + lg * 8]);
#pragma unroll
        for (int ni = 0; ni < 4; ni++)
            bfr[ni] = *(const s16x8*)(&Bs[(wc * 64 + ni * 16 + lr) * 32 + lg * 8]);
#pragma unroll
        for (int mi = 0; mi < 4; mi++)
#pragma unroll
            for (int ni = 0; ni < 4; ni++)
                acc[mi][ni] = __builtin_amdgcn_mfma_f32_16x16x32_bf16(af[mi], bfr[ni], acc[mi][ni], 0, 0, 0);
    }

    if (vt == 0) {
#pragma unroll
        for (int mi = 0; mi < 4; mi++)
#pragma unroll
            for (int ni = 0; ni < 4; ni++)
#pragma unroll
                for (int j = 0; j < 4; j++) {
                    int m = m0 + wr * 64 + mi * 16 + lg * 4 + j;
                    int n = n0 + wc * 64 + ni * 16 + lr;
                    int b = m >> 11, tt = m & (TQ - 1);
                    int h = n >> 6, d = n & 63;
                    outb[((size_t)(b * NH + h) * TQ + tt) * DH + d] = f2bf(acc[mi][ni][j] * scale);
                }
    } else if (vt == 1) {
#pragma unroll
        for (int mi = 0; mi < 4; mi++)
#pragma unroll
            for (int ni = 0; ni < 4; ni++) {
                int m = m0 + wr * 64 + mi * 16 + lg * 4;
                int n = n0 + wc * 64 + ni * 16 + lr;
                int b = m >> 11, tt = m & (TQ - 1);
                int h = n >> 6, d = n & 63;
                ushort4 pk;
                pk.x = f2bf(acc[mi][ni][0] * scale);
                pk.y = f2bf(acc[mi][ni][1] * scale);
                pk.z = f2bf(acc[mi][ni][2] * scale);
                pk.w = f2bf(acc[mi][ni][3] * scale);
                *(ushort4*)(outb + ((size_t)(b * NH + h) * DH + d) * TQ + tt) = pk;
            }
    } else {
#pragma unroll
        for (int mi = 0; mi < 4; mi++)
#pragma unroll
            for (int ni = 0; ni < 4; ni++)
#pragma unroll
                for (int j = 0; j < 4; j++) {
                    int m = m0 + wr * 64 + mi * 16 + lg * 4 + j;
                    int n = n0 + wc * 64 + ni * 16 + lr;
                    outf[(size_t)m * HIDDEN + n] = acc[mi][ni][j];
                }
    }
}

// ---------------------------------------------------------------------------
// Flash attention v4: bias via MFMA C-init, denominator via ones-row MFMA,
// max3-tree row max. Swapped QK (S^T, q=lane&15), in-lane P packing with the
// k-slot permutation, V pre-transposed+permuted, double-buffered LDS.
// ---------------------------------------------------------------------------
__global__ __launch_bounds__(256, 3) void attn_kernel(
        const unsigned short* __restrict__ QP,
        const unsigned short* __restrict__ KP,
        const unsigned short* __restrict__ VT,
        const float* __restrict__ biasF,
        unsigned short* __restrict__ AO) {
    __shared__ alignas(16) unsigned short Ks[2][64 * 72];
    __shared__ alignas(16) unsigned short Vs[2][64 * 72];
    const int t = threadIdx.x, wave = t >> 6, lane = t & 63;
    const int lr = lane & 15, lg = lane >> 4;
    const int bh = blockIdx.y;
    const int q0 = blockIdx.x * 128 + wave * 32;
    const unsigned short* Qb = QP + (size_t)bh * TQ * DH;
    const unsigned short* Kb = KP + (size_t)bh * TQ * DH;
    const unsigned short* Vb = VT + (size_t)bh * DH * TQ;
    const float* biasRow = biasF + (bh & (NB - 1)) * TQ;

    const short ob = (short)0x3F80;                    // bf16 1.0
    const s16x8 ones = {ob, ob, ob, ob, ob, ob, ob, ob};

    s16x8 qf[2][2];
#pragma unroll
    for (int u = 0; u < 2; u++)
#pragma unroll
        for (int h = 0; h < 2; h++)
            qf[u][h] = *(const s16x8*)(Qb + (size_t)(q0 + u * 16 + lr) * DH + h * 32 + lg * 8);

    const int c0 = t, c1 = 256 + t;
    const int sr0 = c0 >> 3, scl0 = (c0 & 7) * 8;
    const int sr1 = c1 >> 3, scl1 = (c1 & 7) * 8;
    const unsigned short* kA0 = Kb + sr0 * DH + scl0;
    const unsigned short* kA1 = Kb + sr1 * DH + scl1;
    const unsigned short* vA0 = Vb + (size_t)sr0 * TQ + scl0;
    const unsigned short* vA1 = Vb + (size_t)sr1 * TQ + scl1;
    const int ksO0 = sr0 * 72 + scl0, ksO1 = sr1 * 72 + scl1;
    const int cc0 = c0 & 7, cc1 = c1 & 7;
    const int vg0 = ((cc0 & 4) << 1) + ((cc0 & 1) << 2) + ((cc0 >> 1) & 1);
    const int vg1 = ((cc1 & 4) << 1) + ((cc1 & 1) << 2) + ((cc1 >> 1) & 1);
    const int vO0 = sr0 * 72 + vg0 * 4, vO1 = sr1 * 72 + vg1 * 4;

    uint4 kr0, kr1, vr0, vr1;
#define LOAD_TILE(kt_) do { \
        kr0 = *(const uint4*)(kA0 + (size_t)(kt_) * 4096); \
        kr1 = *(const uint4*)(kA1 + (size_t)(kt_) * 4096); \
        vr0 = *(const uint4*)(vA0 + (size_t)(kt_) * 64); \
        vr1 = *(const uint4*)(vA1 + (size_t)(kt_) * 64); \
    } while (0)
#define STORE_TILE(b_) do { \
        *(uint4*)(&Ks[b_][ksO0]) = kr0; \
        *(uint4*)(&Ks[b_][ksO1]) = kr1; \
        *(uint2*)(&Vs[b_][vO0])     = make_uint2(vr0.x, vr0.y); \
        *(uint2*)(&Vs[b_][vO0 + 8]) = make_uint2(vr0.z, vr0.w); \
        *(uint2*)(&Vs[b_][vO1])     = make_uint2(vr1.x, vr1.y); \
        *(uint2*)(&Vs[b_][vO1 + 8]) = make_uint2(vr1.z, vr1.w); \
    } while (0)

    f32x4 o[2][4] = {};
    f32x4 osum[2] = {};
    float mrun[2] = {-1e30f, -1e30f};

    LOAD_TILE(0);
    STORE_TILE(0);

    const int NT = TQ / 64;
    for (int kt = 0; kt < NT; kt++) {
        __syncthreads();
        const int cur = kt & 1;
        if (kt + 1 < NT) LOAD_TILE(kt + 1);

        // bias (log2 domain) -> S^T accumulator init (k = kt*64+ni*16+lg*4+r)
        f32x4 z[2][4];
#pragma unroll
        for (int ni = 0; ni < 4; ni++) {
            float4 bv = *(const float4*)(biasRow + kt * 64 + ni * 16 + lg * 4);
            f32x4 zi; zi[0] = bv.x; zi[1] = bv.y; zi[2] = bv.z; zi[3] = bv.w;
            z[0][ni] = zi; z[1][ni] = zi;
        }

#pragma unroll
        for (int ni = 0; ni < 4; ni++) {
            s16x8 kf0 = *(const s16x8*)(&Ks[cur][(ni * 16 + lr) * 72 + lg * 8]);
            s16x8 kf1 = *(const s16x8*)(&Ks[cur][(ni * 16 + lr) * 72 + 32 + lg * 8]);
#pragma unroll
            for (int u = 0; u < 2; u++) {
                z[u][ni] = __builtin_amdgcn_mfma_f32_16x16x32_bf16(kf0, qf[u][0], z[u][ni], 0, 0, 0);
                z[u][ni] = __builtin_amdgcn_mfma_f32_16x16x32_bf16(kf1, qf[u][1], z[u][ni], 0, 0, 0);
            }
        }

        PBU pb[2][2];
#pragma unroll
        for (int u = 0; u < 2; u++) {
            // row max via max3 tree (clang fuses fmaxf pairs to v_max3)
            float a0 = fmaxf(fmaxf(z[u][0][0], z[u][0][1]), z[u][0][2]);
            float a1 = fmaxf(fmaxf(z[u][0][3], z[u][1][0]), z[u][1][1]);
            float a2 = fmaxf(fmaxf(z[u][1][2], z[u][1][3]), z[u][2][0]);
            float a3 = fmaxf(fmaxf(z[u][2][1], z[u][2][2]), z[u][2][3]);
            float a4 = fmaxf(fmaxf(z[u][3][0], z[u][3][1]), z[u][3][2]);
            float vm = fmaxf(fmaxf(fmaxf(a0, a1), a2),
                             fmaxf(fmaxf(a3, a4), z[u][3][3]));
            vm = fmaxf(vm, __shfl_xor(vm, 16));
            vm = fmaxf(vm, __shfl_xor(vm, 32));
            // defer-max (THR=8 in log2 domain)
            if (__any(vm > mrun[u] + 8.f)) {
                float mnew = fmaxf(mrun[u], vm);
                float sc = exp2f(mrun[u] - mnew);
                mrun[u] = mnew;
#pragma unroll
                for (int di = 0; di < 4; di++) {
                    o[u][di][0] *= sc; o[u][di][1] *= sc;
                    o[u][di][2] *= sc; o[u][di][3] *= sc;
                }
                osum[u][0] *= sc; osum[u][1] *= sc;
                osum[u][2] *= sc; osum[u][3] *= sc;
            }
            const float m = mrun[u];
#pragma unroll
            for (int ni = 0; ni < 4; ni++)
#pragma unroll
                for (int r = 0; r < 4; r++)
                    z[u][ni][r] = exp2f(z[u][ni][r] - m);
            // pack P^T B-frags fully in-lane (k-slot permutation)
#pragma unroll
            for (int ks = 0; ks < 2; ks++) {
                pb[u][ks].u4.x = pkbf(z[u][2 * ks][0], z[u][2 * ks][1]);
                pb[u][ks].u4.y = pkbf(z[u][2 * ks][2], z[u][2 * ks][3]);
                pb[u][ks].u4.z = pkbf(z[u][2 * ks + 1][0], z[u][2 * ks + 1][1]);
                pb[u][ks].u4.w = pkbf(z[u][2 * ks + 1][2], z[u][2 * ks + 1][3]);
            }
        }

        // O^T += V^T x P^T ; denominator via ones-row MFMA
#pragma unroll
        for (int di = 0; di < 4; di++)
#pragma unroll
            for (int ks = 0; ks < 2; ks++) {
                s16x8 vf = *(const s16x8*)(&Vs[cur][(di * 16 + lr) * 72 + ks * 32 + lg * 8]);
#pragma unroll
                for (int u = 0; u < 2; u++)
                    o[u][di] = __builtin_amdgcn_mfma_f32_16x16x32_bf16(vf, pb[u][ks].v, o[u][di], 0, 0, 0);
            }
#pragma unroll
        for (int u = 0; u < 2; u++)
#pragma unroll
            for (int ks = 0; ks < 2; ks++)
                osum[u] = __builtin_amdgcn_mfma_f32_16x16x32_bf16(ones, pb[u][ks].v, osum[u], 0, 0, 0);

        if (kt + 1 < NT) STORE_TILE((kt + 1) & 1);
    }

    // epilogue: lane holds q=lr; osum[u][*] = sum for that q (all elems equal)
    const int b = bh >> 4, h = bh & 15;
#pragma unroll
    for (int u = 0; u < 2; u++) {
        float inv = 1.f / osum[u][0];
        int tt = q0 + u * 16 + lr;
#pragma unroll
        for (int di = 0; di < 4; di++) {
            uint2 w;
            w.x = pkbf(o[u][di][0] * inv, o[u][di][1] * inv);
            w.y = pkbf(o[u][di][2] * inv, o[u][di][3] * inv);
            *(uint2*)(AO + (size_t)(b * TQ + tt) * HIDDEN + h * 64 + di * 16 + lg * 4) = w;
        }
    }
#undef LOAD_TILE
#undef STORE_TILE
}

// ---------------------------------------------------------------------------
extern "C" void kernel_launch(void* const* d_in, const int* in_sizes, int n_in,
                              void* d_out, int out_size, void* d_ws, size_t ws_size,
                              hipStream_t stream) {
    const float* q  = (const float*)d_in[0];
    const float* k  = (const float*)d_in[1];
    const float* v  = (const float*)d_in[2];
    const int* pad  = (const int*)d_in[3];
    const float* Wq = (const float*)d_in[4];
    const float* Wk = (const float*)d_in[5];
    const float* Wv = (const float*)d_in[6];
    const float* Wo = (const float*)d_in[7];
    float* out = (float*)d_out;

    // ws (bf16 elems): Wt 4M | Cv 8.39M (AO aliases) | QP 8.39M | KP | VT | biasF
    unsigned short* ws = (unsigned short*)d_ws;
    unsigned short* Wt = ws;
    unsigned short* Cv = ws + (size_t)4 * 1024 * 1024;
    unsigned short* AO = Cv;   // alias: Cv dead after last proj, AO written by attn
    unsigned short* QP = Cv + (size_t)BHN * TQ * DH;
    unsigned short* KP = QP + (size_t)BHN * TQ * DH;
    unsigned short* VTb = KP + (size_t)BHN * TQ * DH;
    float* biasF = (float*)(VTb + (size_t)BHN * TQ * DH);
    (void)ws_size; (void)in_sizes; (void)n_in; (void)out_size;

    dim3 b256(256);
    const dim3 gGemm(8, 64), gCvt(4096);
    maskf_kernel<<<dim3(NB * TQ / 256), b256, 0, stream>>>(pad, biasF);
    wt_kernel<<<dim3(16, 16, 4), b256, 0, stream>>>(Wq, Wk, Wv, Wo, Wt);
    cvt_kernel<<<gCvt, b256, 0, stream>>>(q, Cv);
    gemm_bt<<<gGemm, b256, 0, stream>>>(Cv, Wt + (size_t)0 * 1024 * 1024, QP, nullptr, 0.125f * LOG2E, 0);
    cvt_kernel<<<gCvt, b256, 0, stream>>>(k, Cv);
    gemm_bt<<<gGemm, b256, 0, stream>>>(Cv, Wt + (size_t)1 * 1024 * 1024, KP, nullptr, 1.0f, 0);
    cvt_kernel<<<gCvt, b256, 0, stream>>>(v, Cv);
    gemm_bt<<<gGemm, b256, 0, stream>>>(Cv, Wt + (size_t)2 * 1024 * 1024, VTb, nullptr, 1.0f, 1);
    attn_kernel<<<dim3(TQ / 128, BHN), b256, 0, stream>>>(QP, KP, VTb, biasF, AO);
    gemm_bt<<<gGemm, b256, 0, stream>>>(AO, Wt + (size_t)3 * 1024 * 1024, nullptr, out, 1.0f, 2);
}